// Round 4
// baseline (348.429 us; speedup 1.0000x reference)
//
#include <hip/hip_runtime.h>
#include <hip/hip_bf16.h>

#define D_ 128
#define E_ 100
#define K_ 4
#define C_ 400
#define CH 64     // atom chunks in fallback k_sums
#define GT 2048   // gather: ids staged per LDS tile

// ws layout (f32 slots):
//   [0, 51200)        sums f32[C][D]
//   [51200, 51600)    counts u32[C]
//   [51600, 52000)    cursor u32[C]
//   [52000, 52400)    offsets u32[C]
//   [52400]           loss f32
//   [52401, 52401+N)  sorted int[N]   (primary path only)

// Kernel 1: per-atom argmin over its element's 4 codes, write h_q (f32),
// code as f32 into atom_types slot, LDS histogram -> global u32 counts,
// accumulate commitment loss. 16 lanes per atom, 8 floats per lane.
__global__ __launch_bounds__(256) void k_assign(
    const float* __restrict__ h, const int* __restrict__ ei,
    const float* __restrict__ cb, float* __restrict__ hq,
    float* __restrict__ codes, unsigned* __restrict__ counts,
    float* __restrict__ loss_acc, int N) {
  const int lane16 = threadIdx.x & 15;
  const int gid0 = (blockIdx.x * blockDim.x + threadIdx.x) >> 4;
  const int ngroups = (gridDim.x * blockDim.x) >> 4;
  __shared__ unsigned hist[C_];
  __shared__ float bl;
  for (int i = threadIdx.x; i < C_; i += 256) hist[i] = 0u;
  if (threadIdx.x == 0) bl = 0.f;
  __syncthreads();
  float loss = 0.f;
  for (int a = gid0; a < N; a += ngroups) {
    const float* hrow = h + (size_t)a * D_ + lane16 * 8;
    float4 h0 = reinterpret_cast<const float4*>(hrow)[0];
    float4 h1 = reinterpret_cast<const float4*>(hrow)[1];
    int e = ei[a];
    const float* cbase = cb + (size_t)e * (K_ * D_);
    float p[4];
#pragma unroll
    for (int j = 0; j < 4; ++j) {
      const float* cr = cbase + j * D_ + lane16 * 8;
      float4 c0 = reinterpret_cast<const float4*>(cr)[0];
      float4 c1 = reinterpret_cast<const float4*>(cr)[1];
      float d0 = h0.x - c0.x, d1 = h0.y - c0.y;
      float d2 = h0.z - c0.z, d3 = h0.w - c0.w;
      float d4 = h1.x - c1.x, d5 = h1.y - c1.y;
      float d6 = h1.z - c1.z, d7 = h1.w - c1.w;
      p[j] = ((d0*d0 + d1*d1) + (d2*d2 + d3*d3)) +
             ((d4*d4 + d5*d5) + (d6*d6 + d7*d7));
    }
#pragma unroll
    for (int s = 1; s < 16; s <<= 1) {
#pragma unroll
      for (int j = 0; j < 4; ++j) p[j] += __shfl_xor(p[j], s, 64);
    }
    float bp = p[0]; int best = 0;
    if (p[1] < bp) { bp = p[1]; best = 1; }
    if (p[2] < bp) { bp = p[2]; best = 2; }
    if (p[3] < bp) { bp = p[3]; best = 3; }
    const float* br = cbase + best * D_ + lane16 * 8;
    float4 b0 = reinterpret_cast<const float4*>(br)[0];
    float4 b1 = reinterpret_cast<const float4*>(br)[1];
    float* orow = hq + (size_t)a * D_ + lane16 * 8;
    reinterpret_cast<float4*>(orow)[0] = b0;
    reinterpret_cast<float4*>(orow)[1] = b1;
    if (lane16 == 0) {
      int code = e * K_ + best;
      codes[a] = (float)code;
      loss += bp;
      atomicAdd(&hist[code], 1u);
    }
  }
  __syncthreads();
  if (lane16 == 0) atomicAdd(&bl, loss);
  for (int i = threadIdx.x; i < C_; i += 256) {
    unsigned v = hist[i];
    if (v) atomicAdd(&counts[i], v);
  }
  __syncthreads();
  if (threadIdx.x == 0) atomicAdd(loss_acc, bl);
}

// Kernel 2: exclusive prefix over 400 counts -> offsets, cursor. One block.
__global__ __launch_bounds__(512) void k_prefix(
    const unsigned* __restrict__ counts, unsigned* __restrict__ cursor,
    unsigned* __restrict__ offsets) {
  __shared__ unsigned s[512];
  int t = threadIdx.x;
  unsigned v = (t < C_) ? counts[t] : 0u;
  s[t] = v;
  __syncthreads();
  for (int off = 1; off < 512; off <<= 1) {
    unsigned x = (t >= off) ? s[t - off] : 0u;
    __syncthreads();
    s[t] += x;
    __syncthreads();
  }
  if (t < C_) { unsigned ex = s[t] - v; offsets[t] = ex; cursor[t] = ex; }
}

// Kernel 3: scatter atom ids grouped by code.
__global__ __launch_bounds__(256) void k_scatter(
    const float* __restrict__ codes, unsigned* __restrict__ cursor,
    int* __restrict__ sorted, int N) {
  int stride = gridDim.x * blockDim.x;
  for (int a = blockIdx.x * blockDim.x + threadIdx.x; a < N; a += stride) {
    int code = (int)codes[a];
    unsigned pos = atomicAdd(&cursor[code], 1u);
    sorted[pos] = a;
  }
}

// Kernel 4: gather-sum. Block (c, half): sum h rows of code c over 64 cols.
__global__ __launch_bounds__(256) void k_gather(
    const float* __restrict__ h, const int* __restrict__ sorted,
    const unsigned* __restrict__ offsets, const unsigned* __restrict__ counts,
    float* __restrict__ sums) {
  const int c = blockIdx.x >> 1;
  const int half = blockIdx.x & 1;
  const unsigned off = offsets[c];
  const unsigned cnt = counts[c];
  const int w = threadIdx.x >> 6;
  const int lane = threadIdx.x & 63;
  const int col = lane + half * 64;
  __shared__ int ids[GT];
  __shared__ float red[4][64];
  float acc = 0.f;
  for (unsigned base = 0; base < cnt; base += GT) {
    unsigned n = min((unsigned)GT, cnt - base);
    for (unsigned i = threadIdx.x; i < n; i += 256) ids[i] = sorted[off + base + i];
    __syncthreads();
    for (unsigned i = w; i < n; i += 4) {
      int a = ids[i];
      acc += h[(size_t)a * D_ + col];
    }
    __syncthreads();
  }
  red[w][lane] = acc;
  __syncthreads();
  if (w == 0)
    sums[(size_t)c * D_ + col] = red[0][lane] + red[1][lane] + red[2][lane] + red[3][lane];
}

// Fallback segment-sum (counts come from k_assign's histogram).
__global__ __launch_bounds__(1024) void k_sums(
    const float* __restrict__ h, const float* __restrict__ codes,
    float* __restrict__ sums, int N) {
  const int slice = blockIdx.x & 3;
  const int chunk = blockIdx.x >> 2;
  __shared__ float acc[C_ * 32];
  for (int i = threadIdx.x; i < C_ * 32; i += 1024) acc[i] = 0.f;
  __syncthreads();
  const int apc = N / CH;
  const int a0 = chunk * apc;
  const int sub = threadIdx.x >> 5;
  const int col = threadIdx.x & 31;
  for (int it = 0; it < apc / 32; ++it) {
    int a = a0 + it * 32 + sub;
    int code = (int)codes[a];
    float v = h[(size_t)a * D_ + slice * 32 + col];
    atomicAdd(&acc[code * 32 + col], v);
  }
  __syncthreads();
  for (int i = threadIdx.x; i < C_ * 32; i += 1024)
    atomicAdd(&sums[(size_t)(i >> 5) * D_ + slice * 32 + (i & 31)], acc[i]);
}

// Kernel 5: EMA finalize + loss scalar (u32 counts).
__global__ __launch_bounds__(256) void k_final(
    const float* __restrict__ cb, const float* __restrict__ ecnt,
    const float* __restrict__ esum, const float* __restrict__ ws,
    float* __restrict__ out, int N) {
  const float* sums = ws;
  const unsigned* counts = (const unsigned*)(ws + C_ * D_);
  int idx = blockIdx.x * 256 + threadIdx.x;
  const size_t base = (size_t)N * D_ + N + 1;
  if (idx < C_ * D_) {
    int c = idx >> 7;
    int e4 = (c >> 2) << 2;
    bool present = (counts[e4] + counts[e4 + 1] + counts[e4 + 2] + counts[e4 + 3]) > 0u;
    float es = esum[idx];
    float s  = sums[idx];
    float ns = present ? 0.99f * es + 0.01f * s : es;
    float ec = ecnt[c];
    float nc = present ? 0.99f * ec + 0.01f * (float)counts[c] : ec;
    float ncbv = present ? ns / fmaxf(nc, 1e-5f) : cb[idx];
    out[base + idx] = ncbv;
    if ((idx & 127) == 0) out[base + C_ * D_ + c] = nc;
    out[base + C_ * D_ + C_ + idx] = ns;
  }
  if (idx == 0) {
    float loss = ws[C_ * D_ + C_ * 3 + 1 - 1];  // see layout: loss at 52400
    out[(size_t)N * D_ + N] = 0.25f * loss / ((float)N * (float)D_);
  }
}

extern "C" void kernel_launch(void* const* d_in, const int* in_sizes, int n_in,
                              void* d_out, int out_size, void* d_ws, size_t ws_size,
                              hipStream_t stream) {
  // Identify inputs by size (robust to input-order changes).
  const float* h = nullptr; const int* ei = nullptr;
  const float* cb = nullptr; const float* ecnt = nullptr; const float* esum = nullptr;
  long hsz = -1; int hidx = -1;
  for (int i = 0; i < n_in; ++i)
    if ((long)in_sizes[i] > hsz) { hsz = in_sizes[i]; hidx = i; }
  h = (const float*)d_in[hidx];
  const int N = (int)(hsz / D_);
  for (int i = 0; i < n_in; ++i) {
    if (i == hidx) continue;
    const int s = in_sizes[i];
    if (s == N) ei = (const int*)d_in[i];
    else if (s == C_) ecnt = (const float*)d_in[i];
    else if (s == C_ * D_) { if (!cb) cb = (const float*)d_in[i]; else esum = (const float*)d_in[i]; }
  }

  float* out = (float*)d_out;
  float* hq  = out;
  float* at  = out + (size_t)N * D_;   // atom_types as f32 (also = codes input to scatter)

  float* ws = (float*)d_ws;
  float*    sums    = ws;                                  // [C*D]
  unsigned* counts  = (unsigned*)(ws + C_ * D_);           // [C]
  unsigned* cursor  = (unsigned*)(ws + C_ * D_ + C_);      // [C]
  unsigned* offsets = (unsigned*)(ws + C_ * D_ + 2 * C_);  // [C]
  float*    lossp   = ws + C_ * D_ + 3 * C_;               // [1]
  int*      sorted  = (int*)(ws + C_ * D_ + 3 * C_ + 1);   // [N]

  const size_t need = (size_t)(C_ * D_ + 3 * C_ + 1 + N) * 4;
  const bool primary = ws_size >= need;

  if (primary) {
    // zero counts/cursor/offsets/loss only (sums fully overwritten by k_gather)
    hipMemsetAsync(counts, 0, (size_t)(3 * C_ + 1) * 4, stream);
    k_assign<<<2048, 256, 0, stream>>>(h, ei, cb, hq, at, counts, lossp, N);
    k_prefix<<<1, 512, 0, stream>>>(counts, cursor, offsets);
    k_scatter<<<256, 256, 0, stream>>>(at, cursor, sorted, N);
    k_gather<<<2 * C_, 256, 0, stream>>>(h, sorted, offsets, counts, sums);
  } else {
    hipMemsetAsync(d_ws, 0, (size_t)(C_ * D_ + 3 * C_ + 1) * 4, stream);
    k_assign<<<2048, 256, 0, stream>>>(h, ei, cb, hq, at, counts, lossp, N);
    k_sums<<<CH * 4, 1024, 0, stream>>>(h, at, sums, N);
  }
  k_final<<<(C_ * D_ + 255) / 256, 256, 0, stream>>>(cb, ecnt, esum, ws, out, N);
}

// Round 5
// 213.994 us; speedup vs baseline: 1.6282x; 1.6282x over previous
//
#include <hip/hip_runtime.h>
#include <hip/hip_bf16.h>

#define D_ 128
#define E_ 100
#define K_ 4
#define C_ 400
#define CH 64     // atom chunks in fallback k_sums
#define RPW 32    // sorted rows per wave in k_gather2

// ws layout (f32 slots):
//   [0, C*D)            sums f32[C][D]
//   [C*D, +C)           counts u32[C]
//   [C*D+C, +C)         cursor u32[C]
//   [C*D+2C]            loss f32
//   [C*D+2C+1, +N)      sorted int[N] packed (code<<18)|atom
#define OFF_COUNTS (C_ * D_)
#define OFF_CURSOR (C_ * D_ + C_)
#define OFF_LOSS   (C_ * D_ + 2 * C_)
#define OFF_SORTED (C_ * D_ + 2 * C_ + 1)

// Kernel 1: per-atom argmin over its element's 4 codes, write h_q (f32),
// code as f32 into atom_types slot, LDS histogram -> global u32 counts,
// accumulate commitment loss. 16 lanes per atom, 8 floats per lane.
__global__ __launch_bounds__(256) void k_assign(
    const float* __restrict__ h, const int* __restrict__ ei,
    const float* __restrict__ cb, float* __restrict__ hq,
    float* __restrict__ codes, unsigned* __restrict__ counts,
    float* __restrict__ loss_acc, int N) {
  const int lane16 = threadIdx.x & 15;
  const int gid0 = (blockIdx.x * blockDim.x + threadIdx.x) >> 4;
  const int ngroups = (gridDim.x * blockDim.x) >> 4;
  __shared__ unsigned hist[C_];
  __shared__ float bl;
  for (int i = threadIdx.x; i < C_; i += 256) hist[i] = 0u;
  if (threadIdx.x == 0) bl = 0.f;
  __syncthreads();
  float loss = 0.f;
  for (int a = gid0; a < N; a += ngroups) {
    const float* hrow = h + (size_t)a * D_ + lane16 * 8;
    float4 h0 = reinterpret_cast<const float4*>(hrow)[0];
    float4 h1 = reinterpret_cast<const float4*>(hrow)[1];
    int e = ei[a];
    const float* cbase = cb + (size_t)e * (K_ * D_);
    float p[4];
#pragma unroll
    for (int j = 0; j < 4; ++j) {
      const float* cr = cbase + j * D_ + lane16 * 8;
      float4 c0 = reinterpret_cast<const float4*>(cr)[0];
      float4 c1 = reinterpret_cast<const float4*>(cr)[1];
      float d0 = h0.x - c0.x, d1 = h0.y - c0.y;
      float d2 = h0.z - c0.z, d3 = h0.w - c0.w;
      float d4 = h1.x - c1.x, d5 = h1.y - c1.y;
      float d6 = h1.z - c1.z, d7 = h1.w - c1.w;
      p[j] = ((d0*d0 + d1*d1) + (d2*d2 + d3*d3)) +
             ((d4*d4 + d5*d5) + (d6*d6 + d7*d7));
    }
#pragma unroll
    for (int s = 1; s < 16; s <<= 1) {
#pragma unroll
      for (int j = 0; j < 4; ++j) p[j] += __shfl_xor(p[j], s, 64);
    }
    float bp = p[0]; int best = 0;
    if (p[1] < bp) { bp = p[1]; best = 1; }
    if (p[2] < bp) { bp = p[2]; best = 2; }
    if (p[3] < bp) { bp = p[3]; best = 3; }
    const float* br = cbase + best * D_ + lane16 * 8;
    float4 b0 = reinterpret_cast<const float4*>(br)[0];
    float4 b1 = reinterpret_cast<const float4*>(br)[1];
    float* orow = hq + (size_t)a * D_ + lane16 * 8;
    reinterpret_cast<float4*>(orow)[0] = b0;
    reinterpret_cast<float4*>(orow)[1] = b1;
    if (lane16 == 0) {
      int code = e * K_ + best;
      codes[a] = (float)code;
      loss += bp;
      atomicAdd(&hist[code], 1u);
    }
  }
  __syncthreads();
  if (lane16 == 0) atomicAdd(&bl, loss);
  for (int i = threadIdx.x; i < C_; i += 256) {
    unsigned v = hist[i];
    if (v) atomicAdd(&counts[i], v);
  }
  __syncthreads();
  if (threadIdx.x == 0) atomicAdd(loss_acc, bl);
}

// Kernel 2: exclusive prefix over 400 counts -> cursor. One block.
__global__ __launch_bounds__(512) void k_prefix(
    const unsigned* __restrict__ counts, unsigned* __restrict__ cursor) {
  __shared__ unsigned s[512];
  int t = threadIdx.x;
  unsigned v = (t < C_) ? counts[t] : 0u;
  s[t] = v;
  __syncthreads();
  for (int off = 1; off < 512; off <<= 1) {
    unsigned x = (t >= off) ? s[t - off] : 0u;
    __syncthreads();
    s[t] += x;
    __syncthreads();
  }
  if (t < C_) cursor[t] = s[t] - v;
}

// Kernel 3: scatter packed (code<<18)|atom grouped by code.
__global__ __launch_bounds__(256) void k_scatter(
    const float* __restrict__ codes, unsigned* __restrict__ cursor,
    int* __restrict__ sorted, int N) {
  int stride = gridDim.x * blockDim.x;
  for (int a = blockIdx.x * blockDim.x + threadIdx.x; a < N; a += stride) {
    int code = (int)codes[a];
    unsigned pos = atomicAdd(&cursor[code], 1u);
    sorted[pos] = (code << 18) | a;
  }
}

// Kernel 4: segment sum over sorted order. Each wave owns a contiguous
// RPW-slice of sorted[]; codes are non-decreasing within the slice, so
// register-accumulate full rows (float2/lane) and flush with global
// atomics only on code change + at slice end. Perfect load balance.
__global__ __launch_bounds__(256) void k_gather2(
    const float* __restrict__ h, const int* __restrict__ sorted,
    float* __restrict__ sums, int N) {
  const int wid = (blockIdx.x * 256 + threadIdx.x) >> 6;
  const int lane = threadIdx.x & 63;
  const int base = wid * RPW;
  if (base >= N) return;
  const int end = min(base + RPW, N);
  const float2* h2 = reinterpret_cast<const float2*>(h);
  float2 acc = make_float2(0.f, 0.f);
  int ccur = sorted[base] >> 18;
  for (int i = base; i < end; ++i) {
    int p = sorted[i];
    int c = p >> 18;
    int a = p & 0x3FFFF;
    if (c != ccur) {   // wave-uniform branch (p is uniform per iteration)
      atomicAdd(&sums[ccur * D_ + lane * 2], acc.x);
      atomicAdd(&sums[ccur * D_ + lane * 2 + 1], acc.y);
      acc.x = 0.f; acc.y = 0.f; ccur = c;
    }
    float2 v = h2[(size_t)a * 64 + lane];
    acc.x += v.x; acc.y += v.y;
  }
  atomicAdd(&sums[ccur * D_ + lane * 2], acc.x);
  atomicAdd(&sums[ccur * D_ + lane * 2 + 1], acc.y);
}

// Fallback segment-sum (counts come from k_assign's histogram).
__global__ __launch_bounds__(1024) void k_sums(
    const float* __restrict__ h, const float* __restrict__ codes,
    float* __restrict__ sums, int N) {
  const int slice = blockIdx.x & 3;
  const int chunk = blockIdx.x >> 2;
  __shared__ float acc[C_ * 32];
  for (int i = threadIdx.x; i < C_ * 32; i += 1024) acc[i] = 0.f;
  __syncthreads();
  const int apc = N / CH;
  const int a0 = chunk * apc;
  const int sub = threadIdx.x >> 5;
  const int col = threadIdx.x & 31;
  for (int it = 0; it < apc / 32; ++it) {
    int a = a0 + it * 32 + sub;
    int code = (int)codes[a];
    float v = h[(size_t)a * D_ + slice * 32 + col];
    atomicAdd(&acc[code * 32 + col], v);
  }
  __syncthreads();
  for (int i = threadIdx.x; i < C_ * 32; i += 1024)
    atomicAdd(&sums[(size_t)(i >> 5) * D_ + slice * 32 + (i & 31)], acc[i]);
}

// Kernel 5: EMA finalize + loss scalar (u32 counts).
__global__ __launch_bounds__(256) void k_final(
    const float* __restrict__ cb, const float* __restrict__ ecnt,
    const float* __restrict__ esum, const float* __restrict__ ws,
    float* __restrict__ out, int N) {
  const float* sums = ws;
  const unsigned* counts = (const unsigned*)(ws + OFF_COUNTS);
  int idx = blockIdx.x * 256 + threadIdx.x;
  const size_t base = (size_t)N * D_ + N + 1;
  if (idx < C_ * D_) {
    int c = idx >> 7;
    int e4 = (c >> 2) << 2;
    bool present = (counts[e4] + counts[e4 + 1] + counts[e4 + 2] + counts[e4 + 3]) > 0u;
    float es = esum[idx];
    float s  = sums[idx];
    float ns = present ? 0.99f * es + 0.01f * s : es;
    float ec = ecnt[c];
    float nc = present ? 0.99f * ec + 0.01f * (float)counts[c] : ec;
    float ncbv = present ? ns / fmaxf(nc, 1e-5f) : cb[idx];
    out[base + idx] = ncbv;
    if ((idx & 127) == 0) out[base + C_ * D_ + c] = nc;
    out[base + C_ * D_ + C_ + idx] = ns;
  }
  if (idx == 0) {
    float loss = ws[OFF_LOSS];
    out[(size_t)N * D_ + N] = 0.25f * loss / ((float)N * (float)D_);
  }
}

extern "C" void kernel_launch(void* const* d_in, const int* in_sizes, int n_in,
                              void* d_out, int out_size, void* d_ws, size_t ws_size,
                              hipStream_t stream) {
  // Identify inputs by size (robust to input-order changes).
  const float* h = nullptr; const int* ei = nullptr;
  const float* cb = nullptr; const float* ecnt = nullptr; const float* esum = nullptr;
  long hsz = -1; int hidx = -1;
  for (int i = 0; i < n_in; ++i)
    if ((long)in_sizes[i] > hsz) { hsz = in_sizes[i]; hidx = i; }
  h = (const float*)d_in[hidx];
  const int N = (int)(hsz / D_);
  for (int i = 0; i < n_in; ++i) {
    if (i == hidx) continue;
    const int s = in_sizes[i];
    if (s == N) ei = (const int*)d_in[i];
    else if (s == C_) ecnt = (const float*)d_in[i];
    else if (s == C_ * D_) { if (!cb) cb = (const float*)d_in[i]; else esum = (const float*)d_in[i]; }
  }

  float* out = (float*)d_out;
  float* hq  = out;
  float* at  = out + (size_t)N * D_;   // atom_types as f32 (= codes for scatter)

  float* ws = (float*)d_ws;
  float*    sums   = ws;
  unsigned* counts = (unsigned*)(ws + OFF_COUNTS);
  unsigned* cursor = (unsigned*)(ws + OFF_CURSOR);
  float*    lossp  = ws + OFF_LOSS;
  int*      sorted = (int*)(ws + OFF_SORTED);

  const size_t need = (size_t)(OFF_SORTED + N) * 4;
  const bool primary = ws_size >= need;

  // zero sums/counts/cursor/loss (sums are atomic-accumulated in primary path)
  hipMemsetAsync(d_ws, 0, (size_t)(OFF_LOSS + 1) * 4, stream);

  k_assign<<<2048, 256, 0, stream>>>(h, ei, cb, hq, at, counts, lossp, N);
  if (primary) {
    k_prefix<<<1, 512, 0, stream>>>(counts, cursor);
    k_scatter<<<256, 256, 0, stream>>>(at, cursor, sorted, N);
    const int nwaves = (N + RPW - 1) / RPW;       // 8192
    k_gather2<<<(nwaves + 3) / 4, 256, 0, stream>>>(h, sorted, sums, N);
  } else {
    k_sums<<<CH * 4, 1024, 0, stream>>>(h, at, sums, N);
  }
  k_final<<<(C_ * D_ + 255) / 256, 256, 0, stream>>>(cb, ecnt, esum, ws, out, N);
}

// Round 6
// 167.497 us; speedup vs baseline: 2.0802x; 1.2776x over previous
//
#include <hip/hip_runtime.h>
#include <hip/hip_bf16.h>

#define D_ 128
#define E_ 100
#define K_ 4
#define C_ 400
#define ECH 16        // chunks per element in k_assign
#define SB 64         // escatter blocks

// ws layout (f32 slots):
//   [0, 51200)        sums f32[C][D]      (atomic, zeroed)
//   [51200, 51600)    countsF f32[C]      (atomic, zeroed)
//   [51600]           loss f32            (atomic, zeroed)
//   [51601, 51701)    ehist u32[E]        (atomic, zeroed)
//   [51701, 51801)    eoff u32[E]         (written by eprefix)
//   [51801, 51901)    ecur u32[E]         (written by eprefix)
//   [51901, +N)       sorted int[N]       (atom ids grouped by element)
#define OFF_COUNTS 51200
#define OFF_LOSS   51600
#define OFF_EHIST  51601
#define OFF_EOFF   51701
#define OFF_ECUR   51801
#define OFF_SORTED 51901

__global__ __launch_bounds__(256) void k_ehist(
    const int* __restrict__ ei, unsigned* __restrict__ ehist, int N) {
  __shared__ unsigned lh[E_];
  for (int i = threadIdx.x; i < E_; i += 256) lh[i] = 0u;
  __syncthreads();
  int stride = gridDim.x * 256;
  for (int a = blockIdx.x * 256 + threadIdx.x; a < N; a += stride)
    atomicAdd(&lh[ei[a]], 1u);
  __syncthreads();
  for (int i = threadIdx.x; i < E_; i += 256)
    if (lh[i]) atomicAdd(&ehist[i], lh[i]);
}

__global__ __launch_bounds__(128) void k_eprefix(
    const unsigned* __restrict__ ehist, unsigned* __restrict__ eoff,
    unsigned* __restrict__ ecur) {
  __shared__ unsigned s[128];
  int t = threadIdx.x;
  unsigned v = (t < E_) ? ehist[t] : 0u;
  s[t] = v;
  __syncthreads();
  for (int o = 1; o < 128; o <<= 1) {
    unsigned x = (t >= o) ? s[t - o] : 0u;
    __syncthreads();
    s[t] += x;
    __syncthreads();
  }
  if (t < E_) { unsigned ex = s[t] - v; eoff[t] = ex; ecur[t] = ex; }
}

__global__ __launch_bounds__(256) void k_escatter(
    const int* __restrict__ ei, unsigned* __restrict__ ecur,
    int* __restrict__ sorted, int N) {
  __shared__ unsigned lh[E_], lbase[E_], lcur[E_];
  const int chunk = (N + SB - 1) / SB;
  const int a0 = blockIdx.x * chunk;
  const int a1 = min(a0 + chunk, N);
  for (int i = threadIdx.x; i < E_; i += 256) { lh[i] = 0u; lcur[i] = 0u; }
  __syncthreads();
  for (int a = a0 + threadIdx.x; a < a1; a += 256) atomicAdd(&lh[ei[a]], 1u);
  __syncthreads();
  for (int i = threadIdx.x; i < E_; i += 256)
    lbase[i] = lh[i] ? atomicAdd(&ecur[i], lh[i]) : 0u;
  __syncthreads();
  for (int a = a0 + threadIdx.x; a < a1; a += 256) {
    int e = ei[a];
    unsigned r = atomicAdd(&lcur[e], 1u);
    sorted[lbase[e] + r] = a;
  }
}

// DPP xor-reduce helper (template forces compile-time immediates).
template <int CTRL>
__device__ __forceinline__ float dpp_add(float x) {
  int y = __builtin_amdgcn_update_dpp(0, __builtin_bit_cast(int, x),
                                      CTRL, 0xF, 0xF, true);
  return x + __builtin_bit_cast(float, y);
}

// Fused assign + segment-sum. Block = (element, chunk); 4 waves; wave = 1
// atom/iter, 64 lanes x float2 = full 512B row. Codebook rows in registers.
__global__ __launch_bounds__(256) void k_assign(
    const float* __restrict__ h, const float* __restrict__ cb,
    const int* __restrict__ sorted, const unsigned* __restrict__ eoff,
    const unsigned* __restrict__ ehist, float* __restrict__ hq,
    float* __restrict__ at, float* __restrict__ sums,
    float* __restrict__ countsF, float* __restrict__ lossp, int N) {
  const int e = blockIdx.x / ECH;
  const int k = blockIdx.x % ECH;
  const int cnt = (int)ehist[e];
  const int base = (int)eoff[e];
  const int sz = (cnt + ECH - 1) / ECH;
  const int lo = k * sz;
  const int hi = min(lo + sz, cnt);
  const int w = threadIdx.x >> 6;
  const int lane = threadIdx.x & 63;
  const int e4 = e * K_;
  const float2* h2 = (const float2*)h;
  const float2* cb2 = (const float2*)cb;
  float2* hq2 = (float2*)hq;

  float2 cbr[4];
#pragma unroll
  for (int j = 0; j < 4; ++j) cbr[j] = cb2[(size_t)(e4 + j) * 64 + lane];

  float2 acc[4] = {};
  float cntf[4] = {};
  float lossl = 0.f;

  int i = lo + w;
  int aid = 0; float2 hv = make_float2(0.f, 0.f);
  if (i < hi) { aid = sorted[base + i]; hv = h2[(size_t)aid * 64 + lane]; }
  while (i < hi) {
    int inx = i + 4;
    int aidn = 0; float2 hvn = make_float2(0.f, 0.f);
    if (inx < hi) { aidn = sorted[base + inx]; hvn = h2[(size_t)aidn * 64 + lane]; }

    float p[4];
#pragma unroll
    for (int j = 0; j < 4; ++j) {
      float dx = hv.x - cbr[j].x, dy = hv.y - cbr[j].y;
      p[j] = dx * dx + dy * dy;
    }
#pragma unroll
    for (int j = 0; j < 4; ++j) {
      p[j] = dpp_add<0xB1>(p[j]);    // quad_perm xor1
      p[j] = dpp_add<0x4E>(p[j]);    // quad_perm xor2
      p[j] = dpp_add<0x141>(p[j]);   // row_half_mirror (crosses 4-groups)
      p[j] = dpp_add<0x140>(p[j]);   // row_mirror (crosses 8-groups)
      p[j] += __shfl_xor(p[j], 16, 64);
      p[j] += __shfl_xor(p[j], 32, 64);
    }
    int best = 0; float bp = p[0];
    if (p[1] < bp) { bp = p[1]; best = 1; }
    if (p[2] < bp) { bp = p[2]; best = 2; }
    if (p[3] < bp) { bp = p[3]; best = 3; }

    float2 cq = cbr[0];
    cq = (best == 1) ? cbr[1] : cq;
    cq = (best == 2) ? cbr[2] : cq;
    cq = (best == 3) ? cbr[3] : cq;
    hq2[(size_t)aid * 64 + lane] = cq;
    if (lane == 0) { at[aid] = (float)(e4 + best); lossl += bp; }

#pragma unroll
    for (int j = 0; j < 4; ++j) {
      float m = (best == j) ? 1.f : 0.f;
      acc[j].x = fmaf(m, hv.x, acc[j].x);
      acc[j].y = fmaf(m, hv.y, acc[j].y);
      cntf[j] += m;
    }
    i = inx; aid = aidn; hv = hvn;
  }
  // flush per-wave partials
#pragma unroll
  for (int j = 0; j < 4; ++j) {
    atomicAdd(&sums[(size_t)(e4 + j) * D_ + lane * 2],     acc[j].x);
    atomicAdd(&sums[(size_t)(e4 + j) * D_ + lane * 2 + 1], acc[j].y);
  }
  if (lane == 0) {
#pragma unroll
    for (int j = 0; j < 4; ++j)
      if (cntf[j] != 0.f) atomicAdd(&countsF[e4 + j], cntf[j]);
    if (lossl != 0.f) atomicAdd(lossp, lossl);
  }
}

// EMA finalize + loss scalar (f32 counts).
__global__ __launch_bounds__(256) void k_final(
    const float* __restrict__ cb, const float* __restrict__ ecnt,
    const float* __restrict__ esum, const float* __restrict__ ws,
    float* __restrict__ out, int N) {
  const float* sums = ws;
  const float* countsF = ws + OFF_COUNTS;
  int idx = blockIdx.x * 256 + threadIdx.x;
  const size_t base = (size_t)N * D_ + N + 1;
  if (idx < C_ * D_) {
    int c = idx >> 7;
    int e4 = (c >> 2) << 2;
    bool present = (countsF[e4] + countsF[e4 + 1] + countsF[e4 + 2] + countsF[e4 + 3]) > 0.f;
    float es = esum[idx];
    float s  = sums[idx];
    float ns = present ? 0.99f * es + 0.01f * s : es;
    float ec = ecnt[c];
    float nc = present ? 0.99f * ec + 0.01f * countsF[c] : ec;
    float ncbv = present ? ns / fmaxf(nc, 1e-5f) : cb[idx];
    out[base + idx] = ncbv;
    if ((idx & 127) == 0) out[base + C_ * D_ + c] = nc;
    out[base + C_ * D_ + C_ + idx] = ns;
  }
  if (idx == 0) {
    float loss = ws[OFF_LOSS];
    out[(size_t)N * D_ + N] = 0.25f * loss / ((float)N * (float)D_);
  }
}

extern "C" void kernel_launch(void* const* d_in, const int* in_sizes, int n_in,
                              void* d_out, int out_size, void* d_ws, size_t ws_size,
                              hipStream_t stream) {
  // Identify inputs by size (robust to input-order changes).
  const float* h = nullptr; const int* ei = nullptr;
  const float* cb = nullptr; const float* ecnt = nullptr; const float* esum = nullptr;
  long hsz = -1; int hidx = -1;
  for (int i = 0; i < n_in; ++i)
    if ((long)in_sizes[i] > hsz) { hsz = in_sizes[i]; hidx = i; }
  h = (const float*)d_in[hidx];
  const int N = (int)(hsz / D_);
  for (int i = 0; i < n_in; ++i) {
    if (i == hidx) continue;
    const int s = in_sizes[i];
    if (s == N) ei = (const int*)d_in[i];
    else if (s == C_) ecnt = (const float*)d_in[i];
    else if (s == C_ * D_) { if (!cb) cb = (const float*)d_in[i]; else esum = (const float*)d_in[i]; }
  }

  float* out = (float*)d_out;
  float* hq  = out;
  float* at  = out + (size_t)N * D_;

  float* ws = (float*)d_ws;
  float*    sums    = ws;
  float*    countsF = ws + OFF_COUNTS;
  float*    lossp   = ws + OFF_LOSS;
  unsigned* ehist   = (unsigned*)(ws + OFF_EHIST);
  unsigned* eoff    = (unsigned*)(ws + OFF_EOFF);
  unsigned* ecur    = (unsigned*)(ws + OFF_ECUR);
  int*      sorted  = (int*)(ws + OFF_SORTED);

  // zero sums/counts/loss/ehist in one range
  hipMemsetAsync(d_ws, 0, (size_t)OFF_EOFF * 4, stream);

  k_ehist<<<64, 256, 0, stream>>>(ei, ehist, N);
  k_eprefix<<<1, 128, 0, stream>>>(ehist, eoff, ecur);
  k_escatter<<<SB, 256, 0, stream>>>(ei, ecur, sorted, N);
  k_assign<<<E_ * ECH, 256, 0, stream>>>(h, cb, sorted, eoff, ehist,
                                         hq, at, sums, countsF, lossp, N);
  k_final<<<(C_ * D_ + 255) / 256, 256, 0, stream>>>(cb, ecnt, esum, ws, out, N);
}